// Round 8
// baseline (352.564 us; speedup 1.0000x reference)
//
#include <hip/hip_runtime.h>
#include <stdint.h>

#define M_DIM 16384
#define N_DIM 4096
#define K_DIM 512
#define TPB 8   // m-tiles (128 rows each) per block

typedef int v8i __attribute__((ext_vector_type(8)));
typedef float f32x16 __attribute__((ext_vector_type(16)));
typedef float f32x4v __attribute__((ext_vector_type(4)));

typedef __attribute__((address_space(3))) uint32_t lds_u32_t;
typedef const __attribute__((address_space(1))) uint32_t glob_u32_t;

__device__ __forceinline__ void gload16(const void* g, void* l) {
    __builtin_amdgcn_global_load_lds((glob_u32_t*)g, (lds_u32_t*)l, 16, 0, 0);
}

// one wave per row: fp32 row -> fp8 e4m3 + fp32 sum of squares.
// A (X) rows are written FRAGMENT-MAJOR:
//   Apack[(P*8+ks)*2048 + h*1024 + r*32 + b] = A[32P + r][64ks + 32h + b]
//   (lane covers k in [8*lane, 8*lane+8) -> ks=lane>>3, h=(lane>>2)&1, b=(lane&3)*8)
// B (C) rows are written in natural row-major (k contiguous).
__global__ __launch_bounds__(256)
void convert_norm_kernel(const float* __restrict__ X, const float* __restrict__ C,
                         uint8_t* __restrict__ Apack, uint8_t* __restrict__ Bf8,
                         float* __restrict__ xsq, float* __restrict__ csq) {
    const int wave = threadIdx.x >> 6;
    const int lane = threadIdx.x & 63;
    const int row = blockIdx.x * 4 + wave;

    const float* src;
    uint8_t* dst;
    float* nrm;
    int r;
    size_t off;
    if (row < M_DIM) {
        src = X; dst = Apack; nrm = xsq; r = row;
        off = (size_t)((r >> 5) * 8 + (lane >> 3)) * 2048
            + ((lane >> 2) & 1) * 1024 + (r & 31) * 32 + (lane & 3) * 8;
    } else {
        src = C; dst = Bf8; nrm = csq; r = row - M_DIM;
        off = (size_t)r * K_DIM + lane * 8;
    }

    const float4* p = (const float4*)(src + (size_t)r * K_DIM) + lane * 2;
    float4 a = p[0], b = p[1];
    uint32_t lo = 0, hi = 0;
    lo = __builtin_amdgcn_cvt_pk_fp8_f32(a.x, a.y, lo, false);
    lo = __builtin_amdgcn_cvt_pk_fp8_f32(a.z, a.w, lo, true);
    hi = __builtin_amdgcn_cvt_pk_fp8_f32(b.x, b.y, hi, false);
    hi = __builtin_amdgcn_cvt_pk_fp8_f32(b.z, b.w, hi, true);
    *(uint2*)(dst + off) = make_uint2(lo, hi);

    float s = a.x*a.x + a.y*a.y + a.z*a.z + a.w*a.w
            + b.x*b.x + b.y*b.y + b.z*b.z + b.w*b.w;
    #pragma unroll
    for (int o2 = 32; o2 > 0; o2 >>= 1) s += __shfl_down(s, o2, 64);
    if (lane == 0) nrm[r] = s;
}

// Persistent-strip kernel: block owns a 128-col strip (bn), loops TPB m-tiles.
// B strip (128 cols x 512 k fp8 = 64 KB) staged to LDS ONCE; after the single
// __syncthreads the whole kernel is BARRIER-FREE (B read-only) -> no vmcnt(0)
// drains; A loads, LDS reads, MFMA, exp and NT stores free-flow across waves.
// B LDS layout: row p (col bn+4*(p&31)+(p>>5)), 512 B; within each 128 B kk-seg,
// chunk c stored at slot (c+p)&7 -> swizzle cancels at read (row%8 == r31%8) and
// ds_read_b128 is bank-uniform. A read direct from packed global: lane (r31,h)
// reads 32 B at h*1024 + r31*32 (+16) -> fully coalesced dwordx4 pairs, L2-hot.
// k-chunk identity: A (ks,h) holds global chunks {4ks+2h, 4ks+2h+1}; B read uses
// c0 = 4ks+2h -> identical k-mapping, lane-row-independent on both sides.
__global__ __launch_bounds__(256, 2)
void rbf_mfma_kernel(const uint8_t* __restrict__ Apack, const uint8_t* __restrict__ B8,
                     const float* __restrict__ xsq, const float* __restrict__ csq,
                     float* __restrict__ out) {
    __shared__ uint8_t Bs[128 * 512];   // 64 KB

    const int tid = threadIdx.x;
    const int lv  = tid & 63;
    const int w   = tid >> 6;
    const int h   = lv >> 5;
    const int r31 = lv & 31;

    const int bs = blockIdx.x & 31;     // strip
    const int mg = blockIdx.x >> 5;     // m-group
    const int bn = bs * 128;

    // ---- stage full-K B strip (once) ----
    {
        const int seg = (lv >> 3) & 3;
        const int tc  = lv & 7;
        const int pb  = 2 * w + h;            // == p & 7 for all rounds
        const int cc  = (tc - pb) & 7;
        const int gcb = seg * 8 + cc;         // global 16B k-chunk
        #pragma unroll
        for (int R = 0; R < 16; ++R) {
            const int p = 8 * R + pb;
            const int col = bn + 4 * (p & 31) + (p >> 5);
            gload16(B8 + (size_t)col * K_DIM + gcb * 16,
                    Bs + R * 4096 + w * 1024 + lv * 16);
        }
    }
    __syncthreads();   // the only barrier in the kernel

    const float4 cs4 = *(const float4*)(csq + bn + 4 * r31);

    for (int t = 0; t < TPB; ++t) {
        const int bm = (mg * TPB + t) * 128;
        const uint8_t* aB = Apack + (size_t)((bm >> 5) + w) * 16384
                          + h * 1024 + r31 * 32;

        f32x16 acc[4] = {};

        #pragma unroll
        for (int ks = 0; ks < 8; ++ks) {
            uint4 a0 = *(const uint4*)(aB + ks * 2048);
            uint4 a1 = *(const uint4*)(aB + ks * 2048 + 16);
            v8i av = (v8i){(int)a0.x, (int)a0.y, (int)a0.z, (int)a0.w,
                           (int)a1.x, (int)a1.y, (int)a1.z, (int)a1.w};
            const uint8_t* segp = Bs + (ks >> 1) * 128;
            const int cw = (ks & 1) * 4 + 2 * h;
            const int s0 = ((cw + 0 + r31) & 7) * 16;
            const int s1 = ((cw + 1 + r31) & 7) * 16;
            #pragma unroll
            for (int j = 0; j < 4; ++j) {
                const uint8_t* rowp = segp + (size_t)(j * 32 + r31) * 512;
                uint4 lo = *(const uint4*)(rowp + s0);
                uint4 hi = *(const uint4*)(rowp + s1);
                v8i bv = (v8i){(int)lo.x, (int)lo.y, (int)lo.z, (int)lo.w,
                               (int)hi.x, (int)hi.y, (int)hi.z, (int)hi.w};
                acc[j] = __builtin_amdgcn_mfma_scale_f32_32x32x64_f8f6f4(
                    av, bv, acc[j],
                    0 /*fp8*/, 0 /*fp8*/,
                    0, 0x7F7F7F7Fu, 0, 0x7F7F7F7Fu);
            }
        }

        // ---- epilogue: out = exp(-(xsq - 2*cross + csq)), float4 NT stores ----
        // C/D 32x32: col = lane&31 -> global col bn + 4*r31 + j (col interleave);
        // row = (reg&3) + 8*(reg>>2) + 4h
        const int mbase = bm + 32 * w + 4 * h;
        #pragma unroll
        for (int g = 0; g < 4; ++g) {
            const float4 xs4 = *(const float4*)(xsq + mbase + 8 * g);
            #pragma unroll
            for (int rr = 0; rr < 4; ++rr) {
                const int reg = g * 4 + rr;
                const float xs = (rr == 0) ? xs4.x : (rr == 1) ? xs4.y
                               : (rr == 2) ? xs4.z : xs4.w;
                const int gm = mbase + 8 * g + rr;
                f32x4v o;
                o.x = __expf(-(xs - 2.0f * acc[0][reg] + cs4.x));
                o.y = __expf(-(xs - 2.0f * acc[1][reg] + cs4.y));
                o.z = __expf(-(xs - 2.0f * acc[2][reg] + cs4.z));
                o.w = __expf(-(xs - 2.0f * acc[3][reg] + cs4.w));
                __builtin_nontemporal_store(
                    o, (f32x4v*)(out + (size_t)gm * N_DIM + bn + 4 * r31));
            }
        }
    }
}

extern "C" void kernel_launch(void* const* d_in, const int* in_sizes, int n_in,
                              void* d_out, int out_size, void* d_ws, size_t ws_size,
                              hipStream_t stream) {
    const float* X = (const float*)d_in[0];
    const float* C = (const float*)d_in[1];
    float* out = (float*)d_out;

    uint8_t* Apack = (uint8_t*)d_ws;                          // 8 MB
    uint8_t* Bf8 = Apack + (size_t)M_DIM * K_DIM;             // 2 MB
    float* xsq = (float*)(Bf8 + (size_t)N_DIM * K_DIM);       // 64 KB
    float* csq = xsq + M_DIM;                                 // 16 KB

    convert_norm_kernel<<<(M_DIM + N_DIM) / 4, 256, 0, stream>>>(X, C, Apack, Bf8, xsq, csq);
    rbf_mfma_kernel<<<32 * (M_DIM / 128 / TPB), 256, 0, stream>>>(Apack, Bf8, xsq, csq, out);
}

// Round 9
// 298.314 us; speedup vs baseline: 1.1819x; 1.1819x over previous
//
#include <hip/hip_runtime.h>
#include <stdint.h>

#define M_DIM 16384
#define N_DIM 4096
#define K_DIM 512

typedef int v8i __attribute__((ext_vector_type(8)));
typedef float f32x16 __attribute__((ext_vector_type(16)));
typedef float f32x4v __attribute__((ext_vector_type(4)));

typedef __attribute__((address_space(3))) uint32_t lds_u32_t;
typedef const __attribute__((address_space(1))) uint32_t glob_u32_t;

__device__ __forceinline__ void gload16(const void* g, void* l) {
    __builtin_amdgcn_global_load_lds((glob_u32_t*)g, (lds_u32_t*)l, 16, 0, 0);
}

// one wave per row: fp32 row -> fp8 e4m3 + fp32 sum of squares.
// A (X) rows are written FRAGMENT-MAJOR:
//   Apack[(P*8+ks)*2048 + h*1024 + r*32 + b] = A[32P + r][64ks + 32h + b]
// B (C) rows are written natural row-major (k contiguous).
__global__ __launch_bounds__(256)
void convert_norm_kernel(const float* __restrict__ X, const float* __restrict__ C,
                         uint8_t* __restrict__ Apack, uint8_t* __restrict__ Bf8,
                         float* __restrict__ xsq, float* __restrict__ csq) {
    const int wave = threadIdx.x >> 6;
    const int lane = threadIdx.x & 63;
    const int row = blockIdx.x * 4 + wave;

    const float* src;
    uint8_t* dst;
    float* nrm;
    int r;
    size_t off;
    if (row < M_DIM) {
        src = X; dst = Apack; nrm = xsq; r = row;
        off = (size_t)((r >> 5) * 8 + (lane >> 3)) * 2048
            + ((lane >> 2) & 1) * 1024 + (r & 31) * 32 + (lane & 3) * 8;
    } else {
        src = C; dst = Bf8; nrm = csq; r = row - M_DIM;
        off = (size_t)r * K_DIM + lane * 8;
    }

    const float4* p = (const float4*)(src + (size_t)r * K_DIM) + lane * 2;
    float4 a = p[0], b = p[1];
    uint32_t lo = 0, hi = 0;
    lo = __builtin_amdgcn_cvt_pk_fp8_f32(a.x, a.y, lo, false);
    lo = __builtin_amdgcn_cvt_pk_fp8_f32(a.z, a.w, lo, true);
    hi = __builtin_amdgcn_cvt_pk_fp8_f32(b.x, b.y, hi, false);
    hi = __builtin_amdgcn_cvt_pk_fp8_f32(b.z, b.w, hi, true);
    *(uint2*)(dst + off) = make_uint2(lo, hi);

    float s = a.x*a.x + a.y*a.y + a.z*a.z + a.w*a.w
            + b.x*b.x + b.y*b.y + b.z*b.z + b.w*b.w;
    #pragma unroll
    for (int o2 = 32; o2 > 0; o2 >>= 1) s += __shfl_down(s, o2, 64);
    if (lane == 0) nrm[r] = s;
}

// Block 128x128, 4 waves each 32x128 (1x4 of mfma_scale 32x32x64 fp8, acc=64 VGPR).
// B-ONLY LDS (16 KB, 4 blocks/CU): A slabs are wave-private, so A reads come
// straight from the fragment-packed global buffer (coalesced dwordx4, L2-hot;
// issued before __syncthreads so the barrier's vmcnt(0) drain hides their latency).
// B LDS: row p (128 B) <-> global col bn + 4*(p&31) + (p>>5) (col interleave);
// chunk c of row p at slot (c+p)&7 -> conflict-free ds_read_b128, swizzle cancels
// at read (row % 8 == r31 % 8 on read side... rows read are j*32 + r31).
// k-map identity: A (ks=2kk+ksl, h) holds chunks {kk*8 + ksl*4+2h, +1}; B reads
// chunks {kk*8 + c0, +1}, c0 = ksl*4+2h -> identical, lane-row-independent.
__global__ __launch_bounds__(256, 4)
void rbf_mfma_kernel(const uint8_t* __restrict__ Apack, const uint8_t* __restrict__ B8,
                     const float* __restrict__ xsq, const float* __restrict__ csq,
                     float* __restrict__ out) {
    __shared__ uint8_t Bs[128 * 128];   // 16 KB

    const int tid = threadIdx.x;
    const int lv  = tid & 63;
    const int w   = tid >> 6;
    const int h   = lv >> 5;
    const int r31 = lv & 31;

    const int bn = (blockIdx.x & 31) * 128;   // bn fastest -> A-slab L2 reuse
    const int bm = (blockIdx.x >> 5) * 128;

    // ---- B staging map ----
    const int tr = tid >> 3;            // 0..31
    const int tc = tid & 7;
    const int cc = (tc - tr) & 7;
    const uint8_t* gB = B8 + (size_t)(bn + 4 * tr) * K_DIM + cc * 16;
    uint8_t* BsW = Bs + w * 1024;

    // ---- A fragment base (wave-private 32-row slab, packed) ----
    const uint8_t* aB = Apack + (size_t)((bm >> 5) + w) * 16384 + h * 1024 + r31 * 32;

    const uint8_t* bRow = Bs + r31 * 128;

    f32x16 acc[4] = {};   // 64 VGPRs

    for (int kk = 0; kk < 4; ++kk) {
        const int koff = kk * 128;
        #pragma unroll
        for (int R = 0; R < 4; ++R)
            gload16(gB + koff + (size_t)R * K_DIM, BsW + R * 4096);

        // A loads for this kk — issued before the barrier; its vmcnt(0) drain
        // (structural) covers their L2 latency at zero extra cost.
        uint4 a0[2], a1[2];
        #pragma unroll
        for (int ksl = 0; ksl < 2; ++ksl) {
            const uint8_t* ap = aB + (2 * kk + ksl) * 2048;
            a0[ksl] = *(const uint4*)(ap);
            a1[ksl] = *(const uint4*)(ap + 16);
        }
        __syncthreads();

        #pragma unroll
        for (int ksl = 0; ksl < 2; ++ksl) {
            v8i av = (v8i){(int)a0[ksl].x, (int)a0[ksl].y, (int)a0[ksl].z, (int)a0[ksl].w,
                           (int)a1[ksl].x, (int)a1[ksl].y, (int)a1[ksl].z, (int)a1[ksl].w};
            const int c0 = ksl * 4 + 2 * h;
            const int s0 = ((c0 + 0 + r31) & 7) * 16;
            const int s1 = ((c0 + 1 + r31) & 7) * 16;
            #pragma unroll
            for (int j = 0; j < 4; ++j) {
                uint4 lo = *(const uint4*)(bRow + j * 4096 + s0);
                uint4 hi = *(const uint4*)(bRow + j * 4096 + s1);
                v8i bv = (v8i){(int)lo.x, (int)lo.y, (int)lo.z, (int)lo.w,
                               (int)hi.x, (int)hi.y, (int)hi.z, (int)hi.w};
                acc[j] = __builtin_amdgcn_mfma_scale_f32_32x32x64_f8f6f4(
                    av, bv, acc[j],
                    0 /*fp8*/, 0 /*fp8*/,
                    0, 0x7F7F7F7Fu, 0, 0x7F7F7F7Fu);
            }
        }
        if (kk < 3) __syncthreads();
    }

    // ---- epilogue: out = exp(-(xsq - 2*cross + csq)), float4 NT stores ----
    // C/D 32x32: col = lane&31 -> global col bn + 4*r31 + j (col interleave);
    // row = (reg&3) + 8*(reg>>2) + 4h
    const float4 cs4 = *(const float4*)(csq + bn + 4 * r31);
    const int mbase = bm + 32 * w + 4 * h;

    #pragma unroll
    for (int g = 0; g < 4; ++g) {
        const float4 xs4 = *(const float4*)(xsq + mbase + 8 * g);
        #pragma unroll
        for (int rr = 0; rr < 4; ++rr) {
            const int reg = g * 4 + rr;
            const float xs = (rr == 0) ? xs4.x : (rr == 1) ? xs4.y
                           : (rr == 2) ? xs4.z : xs4.w;
            const int gm = mbase + 8 * g + rr;
            f32x4v o;
            o.x = __expf(-(xs - 2.0f * acc[0][reg] + cs4.x));
            o.y = __expf(-(xs - 2.0f * acc[1][reg] + cs4.y));
            o.z = __expf(-(xs - 2.0f * acc[2][reg] + cs4.z));
            o.w = __expf(-(xs - 2.0f * acc[3][reg] + cs4.w));
            __builtin_nontemporal_store(
                o, (f32x4v*)(out + (size_t)gm * N_DIM + bn + 4 * r31));
        }
    }
}

extern "C" void kernel_launch(void* const* d_in, const int* in_sizes, int n_in,
                              void* d_out, int out_size, void* d_ws, size_t ws_size,
                              hipStream_t stream) {
    const float* X = (const float*)d_in[0];
    const float* C = (const float*)d_in[1];
    float* out = (float*)d_out;

    uint8_t* Apack = (uint8_t*)d_ws;                          // 8 MB
    uint8_t* Bf8 = Apack + (size_t)M_DIM * K_DIM;             // 2 MB
    float* xsq = (float*)(Bf8 + (size_t)N_DIM * K_DIM);       // 64 KB
    float* csq = xsq + M_DIM;                                 // 16 KB

    convert_norm_kernel<<<(M_DIM + N_DIM) / 4, 256, 0, stream>>>(X, C, Apack, Bf8, xsq, csq);
    rbf_mfma_kernel<<<(M_DIM / 128) * (N_DIM / 128), 256, 0, stream>>>(Apack, Bf8, xsq, csq, out);
}